// Round 4
// baseline (62.171 us; speedup 1.0000x reference)
//
#include <hip/hip_runtime.h>

#define BB 4
#define NN 512
#define HH 64
#define NODES (BB*NN)
#define NSL 8            // j-slices == waves per fused block
#define JCH (NN/NSL)     // 64 j's per slice
#define TI 4             // i-nodes per block

typedef float v4f __attribute__((ext_vector_type(4)));

// ---------------- Kernel A: encoder MLP + message projections ----------------
// wave per node, 4 nodes per block (fewer dispatch units than 64-thr blocks).
__global__ __launch_bounds__(256) void enc_kernel(
    const float* __restrict__ pos,
    const float* __restrict__ enc_w1, const float* __restrict__ enc_b1,
    const float* __restrict__ enc_w2, const float* __restrict__ enc_b2,
    const float* __restrict__ msg_w1,
    float* __restrict__ h_out, float* __restrict__ ai_out, float* __restrict__ aj_out)
{
    const int w = threadIdx.x >> 6;
    const int k = threadIdx.x & 63;
    const int node = blockIdx.x*4 + w;
    __shared__ float t_s[4][HH];
    __shared__ float h_s[4][HH];

    const float px = pos[node*2+0];
    const float py = pos[node*2+1];

    float t = fmaf(px, enc_w1[k], fmaf(py, enc_w1[HH + k], enc_b1[k]));
    t_s[w][k] = fmaxf(t, 0.f);
    __syncthreads();

    float h = enc_b2[k];
    #pragma unroll
    for (int m = 0; m < HH; ++m) h = fmaf(t_s[w][m], enc_w2[m*HH + k], h);
    h_s[w][k] = h;
    h_out[node*HH + k] = h;
    __syncthreads();

    float aiv = 0.f, ajv = 0.f;
    #pragma unroll
    for (int m = 0; m < HH; ++m) {
        const float hm = h_s[w][m];
        aiv = fmaf(hm, msg_w1[m*HH + k],        aiv);
        ajv = fmaf(hm, msg_w1[(HH + m)*HH + k], ajv);
    }
    ai_out[node*HH + k] = aiv;
    aj_out[node*HH + k] = ajv;
}

// ---------------- Kernel B: fused pairwise accumulate + output MLP ----------------
// Block = 512 threads = 8 waves; block owns TI=4 consecutive i-nodes.
// Wave w handles j-slice w (64 j's) for all 4 i's (round-3 inner loop),
// writes its partial acc into LDS. After __syncthreads, wave 0 sums the
// slices and runs the whole output MLP (agg->upd->dec) for the 4 nodes with
// v4 weight-row loads (1KB/instr coalesced) and shfl/LDS broadcasts, so each
// weight matrix is read ONCE per block (4-node amortization).
__global__ __launch_bounds__(512, 4) void pairout_kernel(
    const float* __restrict__ pos, const int* __restrict__ box_ptr,
    const float* __restrict__ msg_w1, const float* __restrict__ msg_b1,
    const float* __restrict__ ai, const float* __restrict__ aj,
    const float* __restrict__ h_in,
    const float* __restrict__ msg_w2, const float* __restrict__ msg_b2,
    const float* __restrict__ upd_w1, const float* __restrict__ upd_b1,
    const float* __restrict__ upd_w2, const float* __restrict__ upd_b2,
    const float* __restrict__ dec_w1, const float* __restrict__ dec_b1,
    const float* __restrict__ dec_w2, const float* __restrict__ dec_b2,
    float* __restrict__ out)
{
    const int w  = threadIdx.x >> 6;     // wave id == j-slice
    const int l  = threadIdx.x & 63;
    const int jgrp = l >> 4;
    const int kq   = l & 15;
    const int ig = blockIdx.x;           // 0..511 i-group
    const int b  = ig >> 7;
    const int i0 = (ig & 127) * TI;
    const int node0 = b*NN + i0;
    const int jch0  = w * JCH;

    __shared__ float dbuf[NSL][TI*64];
    __shared__ float acc_lds[NSL][TI][HH];
    __shared__ float C1[TI][HH];
    __shared__ float C2[TI][HH];

    // ================= pair phase (all 8 waves) =================
    {
        const float box  = (float)box_ptr[0];
        const float hbox = 0.5f * box;
        const float2* pos2 = (const float2*)pos;
        float* db = dbuf[w];

        const v4f wd4 = *(const v4f*)(msg_w1 + 2*HH*HH + 4*kq);
        const v4f b1  = *(const v4f*)(msg_b1 + 4*kq);
        v4f base4[TI];
        float2 pi[TI];
        #pragma unroll
        for (int ii = 0; ii < TI; ++ii) {
            base4[ii] = *(const v4f*)(ai + (size_t)(node0 + ii)*HH + 4*kq) + b1;
            pi[ii] = pos2[node0 + ii];
        }

        // distances: lane l handles j = jch0 + l for all TI i's.
        {
            const float2 pj = pos2[b*NN + jch0 + l];
            #pragma unroll
            for (int ii = 0; ii < TI; ++ii) {
                float dx = pj.x - pi[ii].x;
                float dy = pj.y - pi[ii].y;
                dx -= (dx >  hbox) ? box : 0.f;
                dx += (dx < -hbox) ? box : 0.f;
                dy -= (dy >  hbox) ? box : 0.f;
                dy += (dy < -hbox) ? box : 0.f;
                db[ii*64 + (l&3)*16 + (l>>2)] = sqrtf(fmaf(dx, dx, dy*dy));
            }
        }
        __builtin_amdgcn_wave_barrier();

        v4f acc[TI];
        #pragma unroll
        for (int ii = 0; ii < TI; ++ii) acc[ii] = (v4f){0.f,0.f,0.f,0.f};

        #pragma unroll
        for (int t4 = 0; t4 < 4; ++t4) {
            v4f d4[TI];
            #pragma unroll
            for (int ii = 0; ii < TI; ++ii)
                d4[ii] = *(const v4f*)(db + ii*64 + jgrp*16 + 4*t4);
            #pragma unroll
            for (int u = 0; u < 4; ++u) {
                const int o = (t4*4 + u)*4 + jgrp;
                const v4f a4 = *(const v4f*)(aj + (size_t)(b*NN + jch0 + o)*HH + 4*kq);
                #pragma unroll
                for (int ii = 0; ii < TI; ++ii) {
                    const float d = d4[ii][u];
                    v4f t = __builtin_elementwise_fma((v4f)(d), wd4, a4 + base4[ii]);
                    acc[ii] += __builtin_elementwise_max(t, (v4f){0.f,0.f,0.f,0.f});
                }
            }
        }

        // reduce partials across the 4 jgrp lane-groups
        #pragma unroll
        for (int ii = 0; ii < TI; ++ii) {
            #pragma unroll
            for (int c = 0; c < 4; ++c) {
                float v = acc[ii][c];
                v += __shfl_xor(v, 16, 64);
                v += __shfl_xor(v, 32, 64);
                acc[ii][c] = v;
            }
        }

        // self-term (exact: d_ii==0 -> in-loop term == relu(base+aj_i)), write LDS
        {
            const int ii = jgrp;
            const int i  = i0 + ii;
            v4f a = acc[ii];
            if ((i >> 6) == w) {
                const v4f ajs = *(const v4f*)(aj + (size_t)(b*NN + i)*HH + 4*kq);
                a -= __builtin_elementwise_max(base4[ii] + ajs, (v4f){0.f,0.f,0.f,0.f});
            }
            *(v4f*)(&acc_lds[w][ii][4*kq]) = a;
        }
    }
    __syncthreads();
    if (w != 0) return;

    // ================= out phase (wave 0 only; 4 nodes) =================
    // per-lane: jgrp selects the m-subset {4mm+jgrp}, kq selects the k-quad.
    float areg[TI], hreg[TI];
    #pragma unroll
    for (int nn = 0; nn < TI; ++nn) {
        float a = 0.f;
        #pragma unroll
        for (int s = 0; s < NSL; ++s) a += acc_lds[s][nn][l];
        areg[nn] = a;
        hreg[nn] = h_in[(size_t)(node0 + nn)*HH + l];
    }

    const float inv = 1.f / (float)(NN - 1);

    // ---- agg = acc @ msg_w2 * inv + msg_b2  -> C1 ----
    {
        v4f q[TI];
        #pragma unroll
        for (int nn = 0; nn < TI; ++nn) q[nn] = (v4f){0.f,0.f,0.f,0.f};
        #pragma unroll
        for (int mm = 0; mm < 16; ++mm) {
            const int m = 4*mm + jgrp;
            const v4f wrow = *(const v4f*)(msg_w2 + m*HH + 4*kq);
            #pragma unroll
            for (int nn = 0; nn < TI; ++nn) {
                const float am = __shfl(areg[nn], m, 64);
                q[nn] = __builtin_elementwise_fma((v4f)(am), wrow, q[nn]);
            }
        }
        const v4f b2q = *(const v4f*)(msg_b2 + 4*kq);
        #pragma unroll
        for (int nn = 0; nn < TI; ++nn) {
            v4f v = q[nn];
            #pragma unroll
            for (int c = 0; c < 4; ++c) {
                float x = v[c];
                x += __shfl_xor(x, 16, 64);
                x += __shfl_xor(x, 32, 64);
                v[c] = x;
            }
            v = __builtin_elementwise_fma(v, (v4f)(inv), b2q);
            if (jgrp == 0) *(v4f*)(&C1[nn][4*kq]) = v;
        }
        __builtin_amdgcn_wave_barrier();
    }

    // ---- p = relu(h @ upd_w1[:64] + agg @ upd_w1[64:] + upd_b1) -> C2 ----
    {
        v4f q[TI];
        #pragma unroll
        for (int nn = 0; nn < TI; ++nn) q[nn] = (v4f){0.f,0.f,0.f,0.f};
        #pragma unroll
        for (int mm = 0; mm < 16; ++mm) {
            const int m = 4*mm + jgrp;
            const v4f wrow = *(const v4f*)(upd_w1 + m*HH + 4*kq);
            #pragma unroll
            for (int nn = 0; nn < TI; ++nn) {
                const float hm = __shfl(hreg[nn], m, 64);
                q[nn] = __builtin_elementwise_fma((v4f)(hm), wrow, q[nn]);
            }
        }
        #pragma unroll
        for (int mm = 0; mm < 16; ++mm) {
            const int m = 4*mm + jgrp;
            const v4f wrow = *(const v4f*)(upd_w1 + (size_t)(HH + m)*HH + 4*kq);
            #pragma unroll
            for (int nn = 0; nn < TI; ++nn) {
                const float gm = C1[nn][m];
                q[nn] = __builtin_elementwise_fma((v4f)(gm), wrow, q[nn]);
            }
        }
        const v4f b1q = *(const v4f*)(upd_b1 + 4*kq);
        #pragma unroll
        for (int nn = 0; nn < TI; ++nn) {
            v4f v = q[nn];
            #pragma unroll
            for (int c = 0; c < 4; ++c) {
                float x = v[c];
                x += __shfl_xor(x, 16, 64);
                x += __shfl_xor(x, 32, 64);
                v[c] = x;
            }
            v = __builtin_elementwise_max(v + b1q, (v4f){0.f,0.f,0.f,0.f});
            if (jgrp == 0) *(v4f*)(&C2[nn][4*kq]) = v;
        }
        __builtin_amdgcn_wave_barrier();
    }

    // ---- u = p @ upd_w2 + upd_b2 -> C1 ----
    {
        v4f q[TI];
        #pragma unroll
        for (int nn = 0; nn < TI; ++nn) q[nn] = (v4f){0.f,0.f,0.f,0.f};
        #pragma unroll
        for (int mm = 0; mm < 16; ++mm) {
            const int m = 4*mm + jgrp;
            const v4f wrow = *(const v4f*)(upd_w2 + m*HH + 4*kq);
            #pragma unroll
            for (int nn = 0; nn < TI; ++nn) {
                const float pm = C2[nn][m];
                q[nn] = __builtin_elementwise_fma((v4f)(pm), wrow, q[nn]);
            }
        }
        const v4f b2q = *(const v4f*)(upd_b2 + 4*kq);
        #pragma unroll
        for (int nn = 0; nn < TI; ++nn) {
            v4f v = q[nn];
            #pragma unroll
            for (int c = 0; c < 4; ++c) {
                float x = v[c];
                x += __shfl_xor(x, 16, 64);
                x += __shfl_xor(x, 32, 64);
                v[c] = x;
            }
            v = v + b2q;
            if (jgrp == 0) *(v4f*)(&C1[nn][4*kq]) = v;
        }
        __builtin_amdgcn_wave_barrier();
    }

    // ---- d1 = relu(u @ dec_w1 + dec_b1) (registers), forces = d1 @ dec_w2 + dec_b2 ----
    {
        v4f q[TI];
        #pragma unroll
        for (int nn = 0; nn < TI; ++nn) q[nn] = (v4f){0.f,0.f,0.f,0.f};
        #pragma unroll
        for (int mm = 0; mm < 16; ++mm) {
            const int m = 4*mm + jgrp;
            const v4f wrow = *(const v4f*)(dec_w1 + m*HH + 4*kq);
            #pragma unroll
            for (int nn = 0; nn < TI; ++nn) {
                const float um = C1[nn][m];
                q[nn] = __builtin_elementwise_fma((v4f)(um), wrow, q[nn]);
            }
        }
        const v4f db1q = *(const v4f*)(dec_b1 + 4*kq);
        const v4f w2a  = *(const v4f*)(dec_w2 + 8*kq);      // rows 4kq,4kq+1: [x,y,x,y]
        const v4f w2b  = *(const v4f*)(dec_w2 + 8*kq + 4);  // rows 4kq+2,4kq+3
        const float fb0 = dec_b2[0];
        const float fb1 = dec_b2[1];
        #pragma unroll
        for (int nn = 0; nn < TI; ++nn) {
            v4f v = q[nn];
            #pragma unroll
            for (int c = 0; c < 4; ++c) {
                float x = v[c];
                x += __shfl_xor(x, 16, 64);
                x += __shfl_xor(x, 32, 64);
                v[c] = x;
            }
            v = __builtin_elementwise_max(v + db1q, (v4f){0.f,0.f,0.f,0.f});
            float f0 = v[0]*w2a[0] + v[1]*w2a[2] + v[2]*w2b[0] + v[3]*w2b[2];
            float f1 = v[0]*w2a[1] + v[1]*w2a[3] + v[2]*w2b[1] + v[3]*w2b[3];
            #pragma unroll
            for (int off = 1; off <= 8; off <<= 1) {
                f0 += __shfl_xor(f0, off, 64);
                f1 += __shfl_xor(f1, off, 64);
            }
            if (l == 0) {
                out[(size_t)(node0 + nn)*2 + 0] = f0 + fb0;
                out[(size_t)(node0 + nn)*2 + 1] = f1 + fb1;
            }
        }
    }
}

extern "C" void kernel_launch(void* const* d_in, const int* in_sizes, int n_in,
                              void* d_out, int out_size, void* d_ws, size_t ws_size,
                              hipStream_t stream) {
    const float* pos    = (const float*)d_in[0];
    const int*   boxp   = (const int*)  d_in[1];
    const float* enc_w1 = (const float*)d_in[2];
    const float* enc_b1 = (const float*)d_in[3];
    const float* enc_w2 = (const float*)d_in[4];
    const float* enc_b2 = (const float*)d_in[5];
    const float* msg_w1 = (const float*)d_in[6];
    const float* msg_b1 = (const float*)d_in[7];
    const float* msg_w2 = (const float*)d_in[8];
    const float* msg_b2 = (const float*)d_in[9];
    const float* upd_w1 = (const float*)d_in[10];
    const float* upd_b1 = (const float*)d_in[11];
    const float* upd_w2 = (const float*)d_in[12];
    const float* upd_b2 = (const float*)d_in[13];
    const float* dec_w1 = (const float*)d_in[14];
    const float* dec_b1 = (const float*)d_in[15];
    const float* dec_w2 = (const float*)d_in[16];
    const float* dec_b2 = (const float*)d_in[17];

    float* ws = (float*)d_ws;
    float* h  = ws;
    float* ai = ws + (size_t)NODES*HH;
    float* aj = ws + (size_t)2*NODES*HH;

    enc_kernel<<<NODES/4, 256, 0, stream>>>(pos, enc_w1, enc_b1, enc_w2, enc_b2,
                                            msg_w1, h, ai, aj);
    pairout_kernel<<<NODES/TI, 512, 0, stream>>>(pos, boxp, msg_w1, msg_b1,
                                                 ai, aj, h,
                                                 msg_w2, msg_b2,
                                                 upd_w1, upd_b1, upd_w2, upd_b2,
                                                 dec_w1, dec_b1, dec_w2, dec_b2,
                                                 (float*)d_out);
}

// Round 5
// 32.105 us; speedup vs baseline: 1.9365x; 1.9365x over previous
//
#include <hip/hip_runtime.h>

#define BB 4
#define NN 512
#define HH 64
#define NODES (BB*NN)
#define SPLIT 8
#define JCH (NN/SPLIT)   // 64 j's per slice
#define TI 4             // i's per wave (pair kernel)
#define TO 4             // nodes per wave (out kernel)

typedef float v4f __attribute__((ext_vector_type(4)));

// ---------------- Kernel A: encoder MLP + message projections ----------------
// wave per node, 4 waves (4 nodes) per 256-thr block. Lane k owns dim k.
__global__ __launch_bounds__(256) void enc_kernel(
    const float* __restrict__ pos,
    const float* __restrict__ enc_w1, const float* __restrict__ enc_b1,
    const float* __restrict__ enc_w2, const float* __restrict__ enc_b2,
    const float* __restrict__ msg_w1,
    float* __restrict__ h_out, float* __restrict__ ai_out, float* __restrict__ aj_out)
{
    const int w = threadIdx.x >> 6;
    const int k = threadIdx.x & 63;
    const int node = blockIdx.x*4 + w;
    __shared__ float t_s[4][HH];
    __shared__ float h_s[4][HH];

    const float px = pos[node*2+0];
    const float py = pos[node*2+1];

    float t = fmaf(px, enc_w1[k], fmaf(py, enc_w1[HH + k], enc_b1[k]));
    t_s[w][k] = fmaxf(t, 0.f);
    __syncthreads();

    float h = enc_b2[k];
    #pragma unroll
    for (int m = 0; m < HH; ++m) h = fmaf(t_s[w][m], enc_w2[m*HH + k], h);
    h_s[w][k] = h;
    h_out[node*HH + k] = h;
    __syncthreads();

    float aiv = 0.f, ajv = 0.f;
    #pragma unroll
    for (int m = 0; m < HH; ++m) {
        const float hm = h_s[w][m];
        aiv = fmaf(hm, msg_w1[m*HH + k],        aiv);
        ajv = fmaf(hm, msg_w1[(HH + m)*HH + k], ajv);
    }
    ai_out[node*HH + k] = aiv;
    aj_out[node*HH + k] = ajv;
}

// ---------------- Kernel B: pairwise relu-accumulate (round-3, known-good) ----------------
__global__ __launch_bounds__(256) void pair_kernel(
    const float* __restrict__ pos, const int* __restrict__ box_ptr,
    const float* __restrict__ msg_w1, const float* __restrict__ msg_b1,
    const float* __restrict__ ai, const float* __restrict__ aj,
    float* __restrict__ acc_part)
{
    const int w  = threadIdx.x >> 6;
    const int l  = threadIdx.x & 63;
    const int jgrp = l >> 4;
    const int kq   = l & 15;
    const int wj = blockIdx.x*4 + w;          // wave-job id
    const int s  = wj & (SPLIT-1);            // j-slice
    const int ig = wj >> 3;                   // i-group 0..511
    const int b  = ig >> 7;                   // batch (128 groups/batch)
    const int i0 = (ig & 127) * TI;           // local i base
    const int jch0 = s * JCH;                 // j base within batch

    const float box  = (float)box_ptr[0];
    const float hbox = 0.5f * box;

    __shared__ float dbuf[4][TI*64];          // per wave: TI x 64 dist slots
    float* db = dbuf[w];

    const float2* pos2 = (const float2*)pos;

    const v4f wd4 = *(const v4f*)(msg_w1 + 2*HH*HH + 4*kq);
    const v4f b1  = *(const v4f*)(msg_b1 + 4*kq);
    v4f base4[TI];
    float2 pi[TI];
    #pragma unroll
    for (int ii = 0; ii < TI; ++ii) {
        const int node = b*NN + i0 + ii;
        base4[ii] = *(const v4f*)(ai + (size_t)node*HH + 4*kq) + b1;
        pi[ii] = pos2[node];
    }

    // distances: lane l handles j = jch0 + l, all TI i's.
    {
        const float2 pj = pos2[b*NN + jch0 + l];
        #pragma unroll
        for (int ii = 0; ii < TI; ++ii) {
            float dx = pj.x - pi[ii].x;
            float dy = pj.y - pi[ii].y;
            dx -= (dx >  hbox) ? box : 0.f;
            dx += (dx < -hbox) ? box : 0.f;
            dy -= (dy >  hbox) ? box : 0.f;
            dy += (dy < -hbox) ? box : 0.f;
            db[ii*64 + (l&3)*16 + (l>>2)] = sqrtf(fmaf(dx, dx, dy*dy));
        }
    }
    __builtin_amdgcn_wave_barrier();

    v4f acc[TI];
    #pragma unroll
    for (int ii = 0; ii < TI; ++ii) acc[ii] = (v4f){0.f,0.f,0.f,0.f};

    #pragma unroll
    for (int t4 = 0; t4 < 4; ++t4) {
        v4f d4[TI];
        #pragma unroll
        for (int ii = 0; ii < TI; ++ii)
            d4[ii] = *(const v4f*)(db + ii*64 + jgrp*16 + 4*t4);
        #pragma unroll
        for (int u = 0; u < 4; ++u) {
            const int o = (t4*4 + u)*4 + jgrp;
            const v4f a4 = *(const v4f*)(aj + (size_t)(b*NN + jch0 + o)*HH + 4*kq);
            #pragma unroll
            for (int ii = 0; ii < TI; ++ii) {
                const float d = d4[ii][u];
                v4f t = __builtin_elementwise_fma((v4f)(d), wd4, a4 + base4[ii]);
                acc[ii] += __builtin_elementwise_max(t, (v4f){0.f,0.f,0.f,0.f});
            }
        }
    }

    // reduce partials across the 4 jgrp lane-groups
    #pragma unroll
    for (int ii = 0; ii < TI; ++ii) {
        #pragma unroll
        for (int c = 0; c < 4; ++c) {
            float v = acc[ii][c];
            v += __shfl_xor(v, 16, 64);
            v += __shfl_xor(v, 32, 64);
            acc[ii][c] = v;
        }
    }

    // self-term (exact: d_ii==0 -> in-loop term == relu(base+aj_i)); write partial
    {
        const int ii = jgrp;
        const int i  = i0 + ii;
        v4f a = acc[ii];
        if ((i >> 6) == s) {
            const v4f ajs = *(const v4f*)(aj + (size_t)(b*NN + i)*HH + 4*kq);
            a -= __builtin_elementwise_max(base4[ii] + ajs, (v4f){0.f,0.f,0.f,0.f});
        }
        *(v4f*)(acc_part + ((size_t)s*NODES + b*NN + i)*HH + 4*kq) = a;
    }
}

// ---------------- Kernel C: output MLP, 4 nodes per wave ----------------
// Block = 256 thr = 4 waves, each wave independent, owns TO=4 nodes.
// Lane l: jgrp = l>>4 picks m-subset {4mm+jgrp}, kq = l&15 picks k-quad.
// Each 64x64 weight matrix is read ONCE per wave as v4 rows (1KB/instr),
// amortized over 4 nodes; activations live in per-wave LDS buffers.
__global__ __launch_bounds__(256) void out_kernel(
    const float* __restrict__ h_in, const float* __restrict__ acc_in,
    const float* __restrict__ msg_w2, const float* __restrict__ msg_b2,
    const float* __restrict__ upd_w1, const float* __restrict__ upd_b1,
    const float* __restrict__ upd_w2, const float* __restrict__ upd_b2,
    const float* __restrict__ dec_w1, const float* __restrict__ dec_b1,
    const float* __restrict__ dec_w2, const float* __restrict__ dec_b2,
    float* __restrict__ out)
{
    const int w = threadIdx.x >> 6;
    const int l = threadIdx.x & 63;
    const int jgrp = l >> 4;
    const int kq   = l & 15;
    const int node0 = blockIdx.x*16 + w*TO;

    __shared__ float A [4][TO][HH];
    __shared__ float Hs[4][TO][HH];
    __shared__ float G [4][TO][HH];
    __shared__ float P [4][TO][HH];
    __shared__ float U [4][TO][HH];

    // load acc (sum 8 slices) and h; lane l owns dim l
    #pragma unroll
    for (int nn = 0; nn < TO; ++nn) {
        float a = 0.f;
        #pragma unroll
        for (int sl = 0; sl < SPLIT; ++sl)
            a += acc_in[((size_t)sl*NODES + node0 + nn)*HH + l];
        A[w][nn][l]  = a;
        Hs[w][nn][l] = h_in[(size_t)(node0 + nn)*HH + l];
    }
    // within-wave LDS RAW: instruction-ordered (same wave, same arrays)

    const float inv = 1.f / (float)(NN - 1);

    // ---- agg = acc @ msg_w2 * inv + msg_b2 -> G ----
    {
        v4f q[TO];
        #pragma unroll
        for (int nn = 0; nn < TO; ++nn) q[nn] = (v4f){0.f,0.f,0.f,0.f};
        #pragma unroll
        for (int mm = 0; mm < 16; ++mm) {
            const int m = 4*mm + jgrp;
            const v4f wrow = *(const v4f*)(msg_w2 + m*HH + 4*kq);
            #pragma unroll
            for (int nn = 0; nn < TO; ++nn)
                q[nn] = __builtin_elementwise_fma((v4f)(A[w][nn][m]), wrow, q[nn]);
        }
        const v4f b2q = *(const v4f*)(msg_b2 + 4*kq);
        #pragma unroll
        for (int nn = 0; nn < TO; ++nn) {
            v4f v = q[nn];
            #pragma unroll
            for (int c = 0; c < 4; ++c) {
                float x = v[c];
                x += __shfl_xor(x, 16, 64);
                x += __shfl_xor(x, 32, 64);
                v[c] = x;
            }
            v = __builtin_elementwise_fma(v, (v4f)(inv), b2q);
            if (jgrp == 0) *(v4f*)(&G[w][nn][4*kq]) = v;
        }
    }

    // ---- p = relu(h @ upd_w1[:64] + agg @ upd_w1[64:] + upd_b1) -> P ----
    {
        v4f q[TO];
        #pragma unroll
        for (int nn = 0; nn < TO; ++nn) q[nn] = (v4f){0.f,0.f,0.f,0.f};
        #pragma unroll
        for (int mm = 0; mm < 16; ++mm) {
            const int m = 4*mm + jgrp;
            const v4f wrow = *(const v4f*)(upd_w1 + m*HH + 4*kq);
            #pragma unroll
            for (int nn = 0; nn < TO; ++nn)
                q[nn] = __builtin_elementwise_fma((v4f)(Hs[w][nn][m]), wrow, q[nn]);
        }
        #pragma unroll
        for (int mm = 0; mm < 16; ++mm) {
            const int m = 4*mm + jgrp;
            const v4f wrow = *(const v4f*)(upd_w1 + (size_t)(HH + m)*HH + 4*kq);
            #pragma unroll
            for (int nn = 0; nn < TO; ++nn)
                q[nn] = __builtin_elementwise_fma((v4f)(G[w][nn][m]), wrow, q[nn]);
        }
        const v4f b1q = *(const v4f*)(upd_b1 + 4*kq);
        #pragma unroll
        for (int nn = 0; nn < TO; ++nn) {
            v4f v = q[nn];
            #pragma unroll
            for (int c = 0; c < 4; ++c) {
                float x = v[c];
                x += __shfl_xor(x, 16, 64);
                x += __shfl_xor(x, 32, 64);
                v[c] = x;
            }
            v = __builtin_elementwise_max(v + b1q, (v4f){0.f,0.f,0.f,0.f});
            if (jgrp == 0) *(v4f*)(&P[w][nn][4*kq]) = v;
        }
    }

    // ---- u = p @ upd_w2 + upd_b2 -> U ----
    {
        v4f q[TO];
        #pragma unroll
        for (int nn = 0; nn < TO; ++nn) q[nn] = (v4f){0.f,0.f,0.f,0.f};
        #pragma unroll
        for (int mm = 0; mm < 16; ++mm) {
            const int m = 4*mm + jgrp;
            const v4f wrow = *(const v4f*)(upd_w2 + m*HH + 4*kq);
            #pragma unroll
            for (int nn = 0; nn < TO; ++nn)
                q[nn] = __builtin_elementwise_fma((v4f)(P[w][nn][m]), wrow, q[nn]);
        }
        const v4f b2q = *(const v4f*)(upd_b2 + 4*kq);
        #pragma unroll
        for (int nn = 0; nn < TO; ++nn) {
            v4f v = q[nn];
            #pragma unroll
            for (int c = 0; c < 4; ++c) {
                float x = v[c];
                x += __shfl_xor(x, 16, 64);
                x += __shfl_xor(x, 32, 64);
                v[c] = x;
            }
            v = v + b2q;
            if (jgrp == 0) *(v4f*)(&U[w][nn][4*kq]) = v;
        }
    }

    // ---- d1 = relu(u @ dec_w1 + dec_b1); forces = d1 @ dec_w2 + dec_b2 ----
    {
        v4f q[TO];
        #pragma unroll
        for (int nn = 0; nn < TO; ++nn) q[nn] = (v4f){0.f,0.f,0.f,0.f};
        #pragma unroll
        for (int mm = 0; mm < 16; ++mm) {
            const int m = 4*mm + jgrp;
            const v4f wrow = *(const v4f*)(dec_w1 + m*HH + 4*kq);
            #pragma unroll
            for (int nn = 0; nn < TO; ++nn)
                q[nn] = __builtin_elementwise_fma((v4f)(U[w][nn][m]), wrow, q[nn]);
        }
        const v4f db1q = *(const v4f*)(dec_b1 + 4*kq);
        const v4f w2a  = *(const v4f*)(dec_w2 + 8*kq);      // rows 4kq,4kq+1: [x,y,x,y]
        const v4f w2b  = *(const v4f*)(dec_w2 + 8*kq + 4);  // rows 4kq+2,4kq+3
        const float fb0 = dec_b2[0];
        const float fb1 = dec_b2[1];
        #pragma unroll
        for (int nn = 0; nn < TO; ++nn) {
            v4f v = q[nn];
            #pragma unroll
            for (int c = 0; c < 4; ++c) {
                float x = v[c];
                x += __shfl_xor(x, 16, 64);
                x += __shfl_xor(x, 32, 64);
                v[c] = x;
            }
            v = __builtin_elementwise_max(v + db1q, (v4f){0.f,0.f,0.f,0.f});
            float f0 = v[0]*w2a[0] + v[1]*w2a[2] + v[2]*w2b[0] + v[3]*w2b[2];
            float f1 = v[0]*w2a[1] + v[1]*w2a[3] + v[2]*w2b[1] + v[3]*w2b[3];
            #pragma unroll
            for (int off = 1; off <= 8; off <<= 1) {
                f0 += __shfl_xor(f0, off, 64);
                f1 += __shfl_xor(f1, off, 64);
            }
            if (l == 0) {
                out[(size_t)(node0 + nn)*2 + 0] = f0 + fb0;
                out[(size_t)(node0 + nn)*2 + 1] = f1 + fb1;
            }
        }
    }
}

extern "C" void kernel_launch(void* const* d_in, const int* in_sizes, int n_in,
                              void* d_out, int out_size, void* d_ws, size_t ws_size,
                              hipStream_t stream) {
    const float* pos    = (const float*)d_in[0];
    const int*   boxp   = (const int*)  d_in[1];
    const float* enc_w1 = (const float*)d_in[2];
    const float* enc_b1 = (const float*)d_in[3];
    const float* enc_w2 = (const float*)d_in[4];
    const float* enc_b2 = (const float*)d_in[5];
    const float* msg_w1 = (const float*)d_in[6];
    const float* msg_b1 = (const float*)d_in[7];
    const float* msg_w2 = (const float*)d_in[8];
    const float* msg_b2 = (const float*)d_in[9];
    const float* upd_w1 = (const float*)d_in[10];
    const float* upd_b1 = (const float*)d_in[11];
    const float* upd_w2 = (const float*)d_in[12];
    const float* upd_b2 = (const float*)d_in[13];
    const float* dec_w1 = (const float*)d_in[14];
    const float* dec_b1 = (const float*)d_in[15];
    const float* dec_w2 = (const float*)d_in[16];
    const float* dec_b2 = (const float*)d_in[17];

    float* ws   = (float*)d_ws;
    float* h    = ws;
    float* ai   = ws + (size_t)NODES*HH;
    float* aj   = ws + (size_t)2*NODES*HH;
    float* accp = ws + (size_t)3*NODES*HH;   // SPLIT * NODES * HH floats

    enc_kernel<<<NODES/4, 256, 0, stream>>>(pos, enc_w1, enc_b1, enc_w2, enc_b2,
                                            msg_w1, h, ai, aj);
    pair_kernel<<<(NODES/TI)*SPLIT/4, 256, 0, stream>>>(pos, boxp, msg_w1, msg_b1,
                                                        ai, aj, accp);
    out_kernel<<<NODES/16, 256, 0, stream>>>(h, accp, msg_w2, msg_b2,
                                             upd_w1, upd_b1, upd_w2, upd_b2,
                                             dec_w1, dec_b1, dec_w2, dec_b2,
                                             (float*)d_out);
}

// Round 6
// 26.921 us; speedup vs baseline: 2.3094x; 1.1926x over previous
//
#include <hip/hip_runtime.h>

#define BB 4
#define NN 512
#define HH 64
#define NODES (BB*NN)
#define NSL 8            // j-slices == waves per fused block
#define JCH (NN/NSL)     // 64 j's per slice
#define TI 4             // i-nodes per block

typedef float v4f __attribute__((ext_vector_type(4)));

// ---------------- Kernel A: encoder MLP + message projections ----------------
// wave per node, 4 waves (4 nodes) per 256-thr block. Lane k owns dim k.
__global__ __launch_bounds__(256) void enc_kernel(
    const float* __restrict__ pos,
    const float* __restrict__ enc_w1, const float* __restrict__ enc_b1,
    const float* __restrict__ enc_w2, const float* __restrict__ enc_b2,
    const float* __restrict__ msg_w1,
    float* __restrict__ h_out, float* __restrict__ ai_out, float* __restrict__ aj_out)
{
    const int w = threadIdx.x >> 6;
    const int k = threadIdx.x & 63;
    const int node = blockIdx.x*4 + w;
    __shared__ float t_s[4][HH];
    __shared__ float h_s[4][HH];

    const float px = pos[node*2+0];
    const float py = pos[node*2+1];

    float t = fmaf(px, enc_w1[k], fmaf(py, enc_w1[HH + k], enc_b1[k]));
    t_s[w][k] = fmaxf(t, 0.f);
    __syncthreads();

    float h = enc_b2[k];
    #pragma unroll
    for (int m = 0; m < HH; ++m) h = fmaf(t_s[w][m], enc_w2[m*HH + k], h);
    h_s[w][k] = h;
    h_out[node*HH + k] = h;
    __syncthreads();

    float aiv = 0.f, ajv = 0.f;
    #pragma unroll
    for (int m = 0; m < HH; ++m) {
        const float hm = h_s[w][m];
        aiv = fmaf(hm, msg_w1[m*HH + k],        aiv);
        ajv = fmaf(hm, msg_w1[(HH + m)*HH + k], ajv);
    }
    ai_out[node*HH + k] = aiv;
    aj_out[node*HH + k] = ajv;
}

// ---------------- Kernel B: fused pair + output MLP ----------------
// Block = 512 thr = 8 waves, owns TI=4 consecutive i-nodes.
// Pair phase: wave w = j-slice w (R3's proven wave-job: 4 i's x 64 j's, packed
// v4 math, 1KB coalesced aj loads); partial acc -> LDS (no global round-trip).
// Out phase: ALL 8 waves: wave w owns (node = w&3, output-half o = w>>2);
// lane l = (jg8 = l>>3 m-subset, kq8 = l&7 k-quad). Each wave computes its
// 32 outputs over all 64 inputs -> no cross-wave reduction; 3 shfl_xor per
// stage reduce jg8. Weight matrices read once per block-half (L1-shared).
__global__ __launch_bounds__(512, 2) void pairout_kernel(
    const float* __restrict__ pos, const int* __restrict__ box_ptr,
    const float* __restrict__ msg_w1, const float* __restrict__ msg_b1,
    const float* __restrict__ ai, const float* __restrict__ aj,
    const float* __restrict__ h_in,
    const float* __restrict__ msg_w2, const float* __restrict__ msg_b2,
    const float* __restrict__ upd_w1, const float* __restrict__ upd_b1,
    const float* __restrict__ upd_w2, const float* __restrict__ upd_b2,
    const float* __restrict__ dec_w1, const float* __restrict__ dec_b1,
    const float* __restrict__ dec_w2, const float* __restrict__ dec_b2,
    float* __restrict__ out)
{
    const int w  = threadIdx.x >> 6;     // wave id == j-slice
    const int l  = threadIdx.x & 63;
    const int jgrp = l >> 4;
    const int kq   = l & 15;
    const int ig = blockIdx.x;           // 0..511
    const int b  = ig >> 7;
    const int i0 = (ig & 127) * TI;
    const int node0 = b*NN + i0;
    const int jch0  = w * JCH;

    __shared__ float dbuf[NSL][TI*64];
    __shared__ float acc_lds[NSL][TI][HH];
    __shared__ float A [TI][HH];
    __shared__ float Hs[TI][HH];
    __shared__ float G [TI][HH];
    __shared__ float P [TI][HH];
    __shared__ float U [TI][HH];
    __shared__ float D [TI][HH];

    // ================= pair phase (all 8 waves) =================
    {
        const float box  = (float)box_ptr[0];
        const float hbox = 0.5f * box;
        const float2* pos2 = (const float2*)pos;
        float* db = dbuf[w];

        const v4f wd4 = *(const v4f*)(msg_w1 + 2*HH*HH + 4*kq);
        const v4f b1  = *(const v4f*)(msg_b1 + 4*kq);
        v4f base4[TI];
        float2 pi[TI];
        #pragma unroll
        for (int ii = 0; ii < TI; ++ii) {
            base4[ii] = *(const v4f*)(ai + (size_t)(node0 + ii)*HH + 4*kq) + b1;
            pi[ii] = pos2[node0 + ii];
        }

        // distances: lane l handles j = jch0 + l for all TI i's
        {
            const float2 pj = pos2[b*NN + jch0 + l];
            #pragma unroll
            for (int ii = 0; ii < TI; ++ii) {
                float dx = pj.x - pi[ii].x;
                float dy = pj.y - pi[ii].y;
                dx -= (dx >  hbox) ? box : 0.f;
                dx += (dx < -hbox) ? box : 0.f;
                dy -= (dy >  hbox) ? box : 0.f;
                dy += (dy < -hbox) ? box : 0.f;
                db[ii*64 + (l&3)*16 + (l>>2)] = sqrtf(fmaf(dx, dx, dy*dy));
            }
        }
        __builtin_amdgcn_wave_barrier();

        v4f acc[TI];
        #pragma unroll
        for (int ii = 0; ii < TI; ++ii) acc[ii] = (v4f){0.f,0.f,0.f,0.f};

        #pragma unroll
        for (int t4 = 0; t4 < 4; ++t4) {
            v4f d4[TI];
            #pragma unroll
            for (int ii = 0; ii < TI; ++ii)
                d4[ii] = *(const v4f*)(db + ii*64 + jgrp*16 + 4*t4);
            #pragma unroll
            for (int u = 0; u < 4; ++u) {
                const int o = (t4*4 + u)*4 + jgrp;
                const v4f a4 = *(const v4f*)(aj + (size_t)(b*NN + jch0 + o)*HH + 4*kq);
                #pragma unroll
                for (int ii = 0; ii < TI; ++ii) {
                    const float d = d4[ii][u];
                    v4f t = __builtin_elementwise_fma((v4f)(d), wd4, a4 + base4[ii]);
                    acc[ii] += __builtin_elementwise_max(t, (v4f){0.f,0.f,0.f,0.f});
                }
            }
        }

        #pragma unroll
        for (int ii = 0; ii < TI; ++ii) {
            #pragma unroll
            for (int c = 0; c < 4; ++c) {
                float v = acc[ii][c];
                v += __shfl_xor(v, 16, 64);
                v += __shfl_xor(v, 32, 64);
                acc[ii][c] = v;
            }
        }

        // self-term (exact: d_ii==0 -> in-loop term == relu(base+aj_i))
        {
            const int ii = jgrp;
            const int i  = i0 + ii;
            v4f a = acc[ii];
            if ((i >> 6) == w) {
                const v4f ajs = *(const v4f*)(aj + (size_t)(b*NN + i)*HH + 4*kq);
                a -= __builtin_elementwise_max(base4[ii] + ajs, (v4f){0.f,0.f,0.f,0.f});
            }
            *(v4f*)(&acc_lds[w][ii][4*kq]) = a;
        }
    }
    __syncthreads();

    // ================= slice-sum + h load (split across waves) =================
    if (w < 4) {
        float a = 0.f;
        #pragma unroll
        for (int s = 0; s < NSL; ++s) a += acc_lds[s][w][l];
        A[w][l] = a;
    } else {
        const int nn = w - 4;
        Hs[nn][l] = h_in[(size_t)(node0 + nn)*HH + l];
    }
    __syncthreads();

    // ================= out phase (all 8 waves) =================
    const int nn  = w & 3;       // node within block
    const int o   = w >> 2;      // output half (0/1)
    const int jg8 = l >> 3;      // m-subset {8mm+jg8}
    const int kq8 = l & 7;       // k-quad within half
    const int ocol = o*32 + 4*kq8;
    const float inv = 1.f / (float)(NN - 1);

    // ---- stage 1: G = A @ msg_w2 * inv + msg_b2 ----
    {
        v4f q = {0.f,0.f,0.f,0.f};
        #pragma unroll
        for (int mm = 0; mm < 8; ++mm) {
            const int m = 8*mm + jg8;
            const v4f wrow = *(const v4f*)(msg_w2 + m*HH + ocol);
            q = __builtin_elementwise_fma((v4f)(A[nn][m]), wrow, q);
        }
        #pragma unroll
        for (int c = 0; c < 4; ++c) {
            float x = q[c];
            x += __shfl_xor(x, 8, 64);
            x += __shfl_xor(x, 16, 64);
            x += __shfl_xor(x, 32, 64);
            q[c] = x;
        }
        q = __builtin_elementwise_fma(q, (v4f)(inv), *(const v4f*)(msg_b2 + ocol));
        if (jg8 == 0) *(v4f*)(&G[nn][ocol]) = q;
    }
    __syncthreads();

    // ---- stage 2: P = relu(Hs @ upd_w1[:64] + G @ upd_w1[64:] + upd_b1) ----
    {
        v4f q = {0.f,0.f,0.f,0.f};
        #pragma unroll
        for (int mm = 0; mm < 8; ++mm) {
            const int m = 8*mm + jg8;
            const v4f wrow = *(const v4f*)(upd_w1 + m*HH + ocol);
            q = __builtin_elementwise_fma((v4f)(Hs[nn][m]), wrow, q);
        }
        #pragma unroll
        for (int mm = 0; mm < 8; ++mm) {
            const int m = 8*mm + jg8;
            const v4f wrow = *(const v4f*)(upd_w1 + (size_t)(HH + m)*HH + ocol);
            q = __builtin_elementwise_fma((v4f)(G[nn][m]), wrow, q);
        }
        #pragma unroll
        for (int c = 0; c < 4; ++c) {
            float x = q[c];
            x += __shfl_xor(x, 8, 64);
            x += __shfl_xor(x, 16, 64);
            x += __shfl_xor(x, 32, 64);
            q[c] = x;
        }
        q = __builtin_elementwise_max(q + *(const v4f*)(upd_b1 + ocol),
                                      (v4f){0.f,0.f,0.f,0.f});
        if (jg8 == 0) *(v4f*)(&P[nn][ocol]) = q;
    }
    __syncthreads();

    // ---- stage 3: U = P @ upd_w2 + upd_b2 ----
    {
        v4f q = {0.f,0.f,0.f,0.f};
        #pragma unroll
        for (int mm = 0; mm < 8; ++mm) {
            const int m = 8*mm + jg8;
            const v4f wrow = *(const v4f*)(upd_w2 + m*HH + ocol);
            q = __builtin_elementwise_fma((v4f)(P[nn][m]), wrow, q);
        }
        #pragma unroll
        for (int c = 0; c < 4; ++c) {
            float x = q[c];
            x += __shfl_xor(x, 8, 64);
            x += __shfl_xor(x, 16, 64);
            x += __shfl_xor(x, 32, 64);
            q[c] = x;
        }
        q = q + *(const v4f*)(upd_b2 + ocol);
        if (jg8 == 0) *(v4f*)(&U[nn][ocol]) = q;
    }
    __syncthreads();

    // ---- stage 4: D = relu(U @ dec_w1 + dec_b1) ----
    {
        v4f q = {0.f,0.f,0.f,0.f};
        #pragma unroll
        for (int mm = 0; mm < 8; ++mm) {
            const int m = 8*mm + jg8;
            const v4f wrow = *(const v4f*)(dec_w1 + m*HH + ocol);
            q = __builtin_elementwise_fma((v4f)(U[nn][m]), wrow, q);
        }
        #pragma unroll
        for (int c = 0; c < 4; ++c) {
            float x = q[c];
            x += __shfl_xor(x, 8, 64);
            x += __shfl_xor(x, 16, 64);
            x += __shfl_xor(x, 32, 64);
            q[c] = x;
        }
        q = __builtin_elementwise_max(q + *(const v4f*)(dec_b1 + ocol),
                                      (v4f){0.f,0.f,0.f,0.f});
        if (jg8 == 0) *(v4f*)(&D[nn][ocol]) = q;
    }
    __syncthreads();

    // ---- final: forces = D @ dec_w2 + dec_b2 (waves 0-3, one node each) ----
    if (w < 4) {
        const float d = D[w][l];
        float f0 = d * dec_w2[2*l + 0];
        float f1 = d * dec_w2[2*l + 1];
        #pragma unroll
        for (int off = 32; off >= 1; off >>= 1) {
            f0 += __shfl_xor(f0, off, 64);
            f1 += __shfl_xor(f1, off, 64);
        }
        if (l == 0) {
            out[(size_t)(node0 + w)*2 + 0] = f0 + dec_b2[0];
            out[(size_t)(node0 + w)*2 + 1] = f1 + dec_b2[1];
        }
    }
}

extern "C" void kernel_launch(void* const* d_in, const int* in_sizes, int n_in,
                              void* d_out, int out_size, void* d_ws, size_t ws_size,
                              hipStream_t stream) {
    const float* pos    = (const float*)d_in[0];
    const int*   boxp   = (const int*)  d_in[1];
    const float* enc_w1 = (const float*)d_in[2];
    const float* enc_b1 = (const float*)d_in[3];
    const float* enc_w2 = (const float*)d_in[4];
    const float* enc_b2 = (const float*)d_in[5];
    const float* msg_w1 = (const float*)d_in[6];
    const float* msg_b1 = (const float*)d_in[7];
    const float* msg_w2 = (const float*)d_in[8];
    const float* msg_b2 = (const float*)d_in[9];
    const float* upd_w1 = (const float*)d_in[10];
    const float* upd_b1 = (const float*)d_in[11];
    const float* upd_w2 = (const float*)d_in[12];
    const float* upd_b2 = (const float*)d_in[13];
    const float* dec_w1 = (const float*)d_in[14];
    const float* dec_b1 = (const float*)d_in[15];
    const float* dec_w2 = (const float*)d_in[16];
    const float* dec_b2 = (const float*)d_in[17];

    float* ws = (float*)d_ws;
    float* h  = ws;
    float* ai = ws + (size_t)NODES*HH;
    float* aj = ws + (size_t)2*NODES*HH;

    enc_kernel<<<NODES/4, 256, 0, stream>>>(pos, enc_w1, enc_b1, enc_w2, enc_b2,
                                            msg_w1, h, ai, aj);
    pairout_kernel<<<NODES/TI, 512, 0, stream>>>(pos, boxp, msg_w1, msg_b1,
                                                 ai, aj, h,
                                                 msg_w2, msg_b2,
                                                 upd_w1, upd_b1, upd_w2, upd_b2,
                                                 dec_w1, dec_b1, dec_w2, dec_b2,
                                                 (float*)d_out);
}